// Round 3
// baseline (7123.363 us; speedup 1.0000x reference)
//
#include <hip/hip_runtime.h>
#include <hip/hip_bf16.h>
#include <hip/hip_cooperative_groups.h>

namespace cg = cooperative_groups;

// Decoder: T=50 steps, B=64, S=400, V=50000, D=E=H=A=512, POOL=2.
// R3: single persistent cooperative kernel for the whole scan (3 grid syncs/step).

#define T_STEPS 50
#define BB 64
#define SS 400

// output offsets (floats)
#define O_GOUT 0
#define O_HID 819200
#define O_ATTN_LAST 851968
#define O_CTXF 877568
#define O_PG 910336
#define O_GATTN 913536
#define O_COVL 2193536
#define O_COVF 2196736

typedef __attribute__((ext_vector_type(4))) float f4;
typedef __attribute__((ext_vector_type(8))) short s8v;

static __device__ __forceinline__ float bf2f(unsigned short u){
  unsigned v = ((unsigned)u) << 16; return __builtin_bit_cast(float, v);
}
static __device__ __forceinline__ unsigned short f2bf(float f){
  unsigned u = __builtin_bit_cast(unsigned, f);
  unsigned r = (u + 0x7FFFu + ((u >> 16) & 1u)) >> 16;
  return (unsigned short)r;
}
static __device__ __forceinline__ float sigmoidf_(float x){ return 1.f/(1.f+__expf(-x)); }
static __device__ __forceinline__ float tanhf_(float x){ float e=__expf(2.f*x); return 1.f - 2.f/(e+1.f); }

// ---------------- converts ----------------
__global__ void conv_ctx(const float* __restrict__ ctx, unsigned short* __restrict__ out){
  int o = blockIdx.x*256 + threadIdx.x;           // [S][B][E] -> [B][S][E] bf16
  if(o >= SS*BB*512) return;
  int e = o & 511; int b = (o>>9)&63; int s = o>>15;
  out[((b*SS+s)<<9) + e] = f2bf(ctx[o]);
}
__global__ void conv_emb(const int* __restrict__ y, const float* __restrict__ embW,
                         unsigned short* __restrict__ embU){
  int o = blockIdx.x*256+threadIdx.x; if(o>=T_STEPS*BB*512) return;
  int d = o & 511; int i = o>>9;
  embU[o] = f2bf(embW[(long)y[i]*512 + d]);
}
__global__ void conv_wihd(const float* __restrict__ W_ih, unsigned short* __restrict__ out){
  int o = blockIdx.x*256+threadIdx.x; if(o>=1536*512) return;
  int j = o>>9; int d = o&511;
  out[o] = f2bf(W_ih[(long)j*1024 + d]);           // D-part for gi_emb precompute
}
__global__ void conv_preT(const float* __restrict__ W_pre, unsigned short* __restrict__ out){
  int o = blockIdx.x*256+threadIdx.x; if(o>=512*512) return;
  int a = o>>9; int e = o&511;
  out[o] = f2bf(W_pre[(long)e*512 + a]);     // out[a][e]
}
__global__ void conv_roT(const float* __restrict__ W_ro, unsigned short* __restrict__ out){
  int o = blockIdx.x*256+threadIdx.x; if(o>=512*2048) return;
  int n = o>>11; int k = o&2047;
  out[o] = f2bf(W_ro[(long)k*512 + n]);      // out[n][k]
}
// pack GRU weights fragment-ordered: Wp[rg = dg*6 + g*2+op][ki 0..15][lane][8]
// dims d = dg*16 + (lane&15); op0 = W_ih E-part, op1 = W_hh
__global__ void conv_wgru(const float* __restrict__ W_ih, const float* __restrict__ W_hh,
                          unsigned short* __restrict__ Wp){
  int o = blockIdx.x*256+threadIdx.x; if(o >= 192*8192) return;
  int rg = o >> 13; int rem = o & 8191;
  int ki = rem >> 9; int ln = (rem >> 3) & 63; int e = o & 7;
  int dg = rg/6; int r3 = rg%6; int g = r3>>1; int op = r3&1;
  int rl = ln & 15; int kk = ((ln>>4)<<3) + e;
  int d = dg*16 + rl; int j = g*512 + d; int k = ki*32 + kk;
  float v = op ? W_hh[(long)j*512 + k] : W_ih[(long)j*1024 + 512 + k];
  Wp[o] = f2bf(v);
}
// pack W_q (h-part rows) per 32-k slice: WqP[dgq 0..15][nrg 0..31][lane][8]
__global__ void conv_wq2(const float* __restrict__ W_q, unsigned short* __restrict__ Wp){
  int o = blockIdx.x*256+threadIdx.x; if(o >= 262144) return;
  int dgq = o >> 14; int r = o & 16383;
  int nrg = r >> 9; int ln = (r>>3)&63; int e = o & 7;
  int n = nrg*16 + (ln&15);
  int k = dgq*32 + ((ln>>4)<<3) + e;
  Wp[o] = f2bf(W_q[(long)k*512 + n]);
}
__global__ void k_init(const float* __restrict__ hidden, const float* __restrict__ init_att,
                       const float* __restrict__ gctx, const float* __restrict__ coverage,
                       unsigned short* __restrict__ h0bf_init, unsigned short* __restrict__ ctx0bf,
                       float* __restrict__ gctxT, float* __restrict__ cov){
  int o = blockIdx.x*256+threadIdx.x;
  if(o < 32768){ h0bf_init[o] = f2bf(hidden[o]); }
  else if(o < 65536){ int p=o-32768; ctx0bf[p] = f2bf(init_att[p]); }
  else if(o < 98304){ int p=o-65536; int b=p>>9,e=p&511; gctxT[e*64+b]=gctx[p]; }
  else if(o < 98304+25600){ int p=o-98304; cov[p]=coverage[p]; }
}

// ---------------- MFMA GEMM: C[M][N] = A[M][K](bf16,row-major) * B[N][Ktot](bf16,n-major)^T ----------
template<int OUT_BF16, int ACCUM>
__global__ __launch_bounds__(256) void mfma_gemm(
    const unsigned short* __restrict__ Abf, int lda,
    const unsigned short* __restrict__ Bbf, int ldb, int koff,
    void* __restrict__ Cp, int ldc, const float* __restrict__ bias, int K)
{
  __shared__ __align__(16) unsigned short Ash[128*40];
  __shared__ __align__(16) unsigned short Bsh[128*40];
  int m0 = blockIdx.x*128, n0 = blockIdx.y*128;
  int tid = threadIdx.x;
  int wid = tid>>6, lane = tid&63;
  int wm = wid>>1, wn = wid&1;
  int lr = lane&15, lg = lane>>4;
  f4 acc[4][4];
  #pragma unroll
  for(int i=0;i<4;i++)
    #pragma unroll
    for(int j=0;j<4;j++) acc[i][j]=(f4)0.f;

  for(int kt=0; kt<K; kt+=32){
    #pragma unroll
    for(int c=0;c<2;c++){
      int flat = tid*16 + c*8;
      int row = flat>>5, col = flat&31;
      const unsigned short* ga = Abf + (long)(m0+row)*lda + kt + col;
      *(uint4*)(&Ash[row*40+col]) = *(const uint4*)ga;
      const unsigned short* gb = Bbf + (long)(n0+row)*ldb + koff + kt + col;
      *(uint4*)(&Bsh[row*40+col]) = *(const uint4*)gb;
    }
    __syncthreads();
    s8v av[4], bv[4];
    #pragma unroll
    for(int mi=0;mi<4;mi++) av[mi] = *(const s8v*)(&Ash[(wm*64+mi*16+lr)*40 + lg*8]);
    #pragma unroll
    for(int ni=0;ni<4;ni++) bv[ni] = *(const s8v*)(&Bsh[(wn*64+ni*16+lr)*40 + lg*8]);
    #pragma unroll
    for(int mi=0;mi<4;mi++)
      #pragma unroll
      for(int ni=0;ni<4;ni++)
        acc[mi][ni] = __builtin_amdgcn_mfma_f32_16x16x32_bf16(av[mi], bv[ni], acc[mi][ni], 0,0,0);
    __syncthreads();
  }
  #pragma unroll
  for(int mi=0;mi<4;mi++)
    #pragma unroll
    for(int ni=0;ni<4;ni++){
      int gc = n0 + wn*64 + ni*16 + lr;
      #pragma unroll
      for(int r=0;r<4;r++){
        int gr = m0 + wm*64 + mi*16 + lg*4 + r;
        float v = acc[mi][ni][r];
        if(bias) v += bias[gc];
        if(OUT_BF16){
          ((unsigned short*)Cp)[(long)gr*ldc + gc] = f2bf(v);
        } else {
          float* C = (float*)Cp;
          if(ACCUM) v += C[(long)gr*ldc+gc];
          C[(long)gr*ldc+gc] = v;
        }
      }
    }
}

// ---------------- small fp32 GEMM (one-time precompute only) ----------------
__global__ __launch_bounds__(256) void small_gemm_kn(
  const float* __restrict__ AT, const float* __restrict__ W, int koff, int N,
  const float* __restrict__ addend, float* __restrict__ out, int K)
{
  int tid = threadIdx.x;
  int b = tid&63; int nq = tid>>6;
  int n = __builtin_amdgcn_readfirstlane(blockIdx.x*4 + nq);
  float acc = addend ? addend[b*N+n] : 0.f;
  const float* wp = W + (long)koff*N + n;
  #pragma unroll 8
  for(int k=0;k<512;k++){
    acc = fmaf(AT[k*64+b], wp[(long)k*N], acc);
  }
  (void)K;
  out[b*N+n] = acc;
}

// ---------------- persistent cooperative scan ----------------
__global__ __launch_bounds__(256, 1) void k_scan(
  const unsigned short* __restrict__ Wgru,
  const unsigned short* __restrict__ WqP,
  const unsigned short* __restrict__ pre,
  const unsigned short* __restrict__ ctxbf,
  unsigned short* __restrict__ ctx_all,
  unsigned short* __restrict__ h0bf_all,
  const unsigned short* __restrict__ ctx0bf,
  const unsigned short* __restrict__ h0bf_init,
  const float* __restrict__ hidden,
  const float* __restrict__ gi_emb,
  const float* __restrict__ b_hh,
  const float* __restrict__ q_g,
  float* __restrict__ qpart,
  const float* __restrict__ Wv,
  const float* __restrict__ Wcov,
  const float* __restrict__ padm,
  float* __restrict__ cov,
  float* __restrict__ energy_g,
  float* __restrict__ outp)
{
  cg::grid_group grid = cg::this_grid();
  __shared__ __align__(16) unsigned short AS[2*16*512];    // 32KB staged ctx/h rows
  __shared__ __align__(16) unsigned short HS[16*32];       // h slice for q-part
  __shared__ float q_sh[512];
  __shared__ float wv_sh[512];
  __shared__ float wcov_sh[512];
  __shared__ float sm[400];
  __shared__ float red[256];
  __shared__ float pb[4][128];

  const int blk = blockIdx.x;
  const int tid = threadIdx.x;
  const int w = tid>>6, lane = tid&63;
  const int lr = lane&15, lg = lane>>4;

  { int n = tid*2; wv_sh[n]=Wv[n]; wv_sh[n+1]=Wv[n+1]; wcov_sh[n]=Wcov[n]; wcov_sh[n+1]=Wcov[n+1]; }

  const int mi_blk = blk>>4;          // 0..3 batch quarter (P1, blk<64)
  const int dgq = blk&15;             // 0..15
  const int dg = dgq*2 + w;           // valid for w<2
  const int d_dim = dg*16 + lr;
  const int brow = mi_blk*16 + lg*4;

  float h_reg[4] = {0.f,0.f,0.f,0.f};
  if(blk<64 && w<2){
    #pragma unroll
    for(int r=0;r<4;r++) h_reg[r] = hidden[(long)(brow+r)*512 + d_dim];
  }
  const int b2 = blk>>2;              // P2 batch index
  const int sq = blk&3;               // s-quarter (P2a) / e-quarter (P2b)

  for(int t=0;t<T_STEPS;t++){
    // ---- P1: GRU + q-partials (blocks 0..63) ----
    if(blk<64){
      const unsigned short* ctxprev = t ? (ctx_all + (long)(t-1)*32768) : ctx0bf;
      const unsigned short* hprev   = t ? (h0bf_all + (long)(t-1)*32768) : h0bf_init;
      for(int c=tid;c<2048;c+=256){
        int op = c>>10; int row=(c>>6)&15; int kc=c&63;
        const unsigned short* src = (op?hprev:ctxprev) + (long)(mi_blk*16+row)*512 + kc*8;
        uint4 v = *(const uint4*)src;
        *(uint4*)((char*)AS + op*16384 + row*1024 + ((kc*16) ^ ((row&7)<<4))) = v;
      }
      __syncthreads();
      if(w<2){
        f4 acc[6];
        #pragma unroll
        for(int u=0;u<6;u++) acc[u]=(f4)0.f;
        const int swz = (lr&7)<<4;
        #pragma unroll 2
        for(int ki=0;ki<16;ki++){
          s8v av0 = *(const s8v*)((const char*)AS + lr*1024 + ((ki*64 + lg*16) ^ swz));
          s8v av1 = *(const s8v*)((const char*)AS + 16384 + lr*1024 + ((ki*64 + lg*16) ^ swz));
          const unsigned short* wb = Wgru + (long)dg*6*8192 + ki*512 + lane*8;
          #pragma unroll
          for(int u=0;u<6;u++){
            s8v bv = *(const s8v*)(wb + (long)u*8192);
            acc[u] = __builtin_amdgcn_mfma_f32_16x16x32_bf16((u&1)?av1:av0, bv, acc[u], 0,0,0);
          }
        }
        float bhr=b_hh[d_dim], bhz=b_hh[512+d_dim], bhn=b_hh[1024+d_dim];
        #pragma unroll
        for(int r=0;r<4;r++){
          int b = brow + r;
          const float* ge = gi_emb + (long)(t*64+b)*1536;
          float rr = sigmoidf_(ge[d_dim]      + bhr + acc[0][r] + acc[1][r]);
          float zz = sigmoidf_(ge[512+d_dim]  + bhz + acc[2][r] + acc[3][r]);
          float nn = tanhf_(  ge[1024+d_dim]        + acc[4][r] + rr*(acc[5][r] + bhn));
          float hv = (1.f-zz)*nn + zz*h_reg[r];
          h_reg[r]=hv;
          unsigned short hb = f2bf(hv);
          h0bf_all[(long)(t*64+b)*512 + d_dim] = hb;
          HS[(lg*4+r)*32 + w*16 + lr] = hb;
          if(t==T_STEPS-1) outp[O_HID + b*512 + d_dim] = hv;
        }
      }
      __syncthreads();
      // q-partials: all 4 waves, nrg = w*8+i
      {
        s8v av = *(const s8v*)(HS + lr*32 + lg*8);
        f4 zero = (f4)0.f;
        f4 aq[8];
        #pragma unroll
        for(int i=0;i<8;i++){
          s8v bv = *(const s8v*)(WqP + (long)dgq*16384 + (w*8+i)*512 + lane*8);
          aq[i] = __builtin_amdgcn_mfma_f32_16x16x32_bf16(av, bv, zero, 0,0,0);
        }
        #pragma unroll
        for(int i=0;i<8;i++)
          #pragma unroll
          for(int r=0;r<4;r++)
            qpart[(long)dgq*32768 + (long)(mi_blk*16+lg*4+r)*512 + (w*8+i)*16 + lr] = aq[i][r];
      }
    }
    grid.sync();
    // ---- P2a: q-reduce + energy (all 256 blocks; b2 x s-quarter) ----
    {
      int n = tid*2;
      float2 s01 = *(const float2*)(q_g + (long)b2*512 + n);
      #pragma unroll
      for(int dq=0;dq<16;dq++){
        float2 v = *(const float2*)(qpart + (long)dq*32768 + (long)b2*512 + n);
        s01.x += v.x; s01.y += v.y;
      }
      q_sh[n]=s01.x; q_sh[n+1]=s01.y;
      __syncthreads();
      if(tid<200){
        int s = sq*100 + (tid>>1);
        int half = tid&1;
        int a0 = half*256;
        float cv = cov[b2*400+s];
        const unsigned short* rp = pre + (((long)(b2*400+s))<<9) + a0;
        float part=0.f;
        #pragma unroll 4
        for(int j=0;j<32;j++){
          uint4 uv = *(const uint4*)(rp + j*8);
          const unsigned* uu = (const unsigned*)&uv;
          #pragma unroll
          for(int q4=0;q4<4;q4++){
            int a = a0 + j*8 + q4*2;
            float lo = bf2f((unsigned short)(uu[q4]&0xffffu));
            float hi = bf2f((unsigned short)(uu[q4]>>16));
            part += wv_sh[a]  * tanhf_(lo + q_sh[a]   + cv*wcov_sh[a]);
            part += wv_sh[a+1]* tanhf_(hi + q_sh[a+1] + cv*wcov_sh[a+1]);
          }
        }
        part += __shfl_xor(part, 1, 64);
        if(half==0)
          energy_g[b2*400+s] = (padm[b2*400+s]>0.5f) ? -1e18f : part;
      }
    }
    grid.sync();
    // ---- P2b: softmax + coverage + context (all 256 blocks; b2 x e-quarter) ----
    {
      float v1 = energy_g[b2*400+tid];
      bool has2 = tid<144;
      float v2 = has2 ? energy_g[b2*400+256+tid] : -INFINITY;
      red[tid]=fmaxf(v1,v2); __syncthreads();
      for(int o=128;o;o>>=1){ if(tid<o) red[tid]=fmaxf(red[tid],red[tid+o]); __syncthreads(); }
      float mx = red[0]; __syncthreads();
      float p1=__expf(v1-mx), p2=has2?__expf(v2-mx):0.f;
      red[tid]=p1+p2; __syncthreads();
      for(int o=128;o;o>>=1){ if(tid<o) red[tid]+=red[tid+o]; __syncthreads(); }
      float inv = 1.f/red[0]; __syncthreads();
      float a1=p1*inv, a2=p2*inv;
      sm[tid]=a1; if(has2) sm[256+tid]=a2;
      if(sq==0){
        float* gat = outp + O_GATTN + (long)t*25600 + b2*400;
        gat[tid]=a1;
        float c1 = cov[b2*400+tid];
        float cl = fminf(a1,c1);
        float nc1 = c1+a1;
        cov[b2*400+tid]=nc1;
        if(t==T_STEPS-1){ outp[O_ATTN_LAST + b2*400 + tid]=a1; outp[O_COVF + b2*400 + tid]=nc1; }
        if(has2){
          gat[256+tid]=a2;
          float c2=cov[b2*400+256+tid];
          cl += fminf(a2,c2);
          float nc2=c2+a2;
          cov[b2*400+256+tid]=nc2;
          if(t==T_STEPS-1){ outp[O_ATTN_LAST + b2*400+256+tid]=a2; outp[O_COVF + b2*400+256+tid]=nc2; }
        }
        red[tid]=cl; __syncthreads();
        for(int o=128;o;o>>=1){ if(tid<o) red[tid]+=red[tid+o]; __syncthreads(); }
        if(tid==0) outp[O_COVL + t*64 + b2]=red[0];
      }
      __syncthreads();
      int ep = (tid&63)*2; int sp = tid>>6;
      int e = sq*128 + ep;
      float acc0=0.f, acc1=0.f;
      for(int s=sp;s<400;s+=4){
        float av = sm[s];
        unsigned u = *(const unsigned*)(ctxbf + (((long)(b2*400+s))<<9) + e);
        acc0 = fmaf(av, bf2f((unsigned short)(u&0xffffu)), acc0);
        acc1 = fmaf(av, bf2f((unsigned short)(u>>16)), acc1);
      }
      pb[sp][ep]=acc0; pb[sp][ep+1]=acc1; __syncthreads();
      if(tid<128){
        int c=tid; int eg = sq*128+c;
        float sum = pb[0][c]+pb[1][c]+pb[2][c]+pb[3][c];
        ctx_all[((long)(t*64+b2)<<9)+eg] = f2bf(sum);
        if(t==T_STEPS-1) outp[O_CTXF + b2*512 + eg] = sum;
      }
      __syncthreads();
    }
    grid.sync();
  }
}

// ---------------- post-pass ----------------
__global__ __launch_bounds__(256) void k_pgen(
  const unsigned short* __restrict__ embU, const unsigned short* __restrict__ h0bf,
  const unsigned short* __restrict__ ctxA, const float* __restrict__ Wpg,
  const float* __restrict__ bpg, float* __restrict__ outp)
{
  int wid = threadIdx.x>>6, lane=threadIdx.x&63;
  int m = blockIdx.x*4 + wid;
  float acc=0.f;
  #pragma unroll
  for(int i=0;i<8;i++){
    int k = i*64+lane;
    acc = fmaf(bf2f(ctxA[(long)m*512+k]), Wpg[k], acc);
    acc = fmaf(bf2f(h0bf[(long)m*512+k]), Wpg[512+k], acc);
    acc = fmaf(bf2f(embU[(long)m*512+k]), Wpg[1024+k], acc);
  }
  #pragma unroll
  for(int off=32; off; off>>=1) acc += __shfl_xor(acc, off, 64);
  if(lane==0) outp[O_PG + m] = sigmoidf_(acc + bpg[0]);
}

__global__ void k_maxout(const float* __restrict__ RO, const float* __restrict__ ro_g,
                         float* __restrict__ outp){
  int o = blockIdx.x*256+threadIdx.x; if(o>=819200) return;
  int h = o & 255; int m = o>>8; int b = m & 63;
  float v0 = RO[(long)m*512 + 2*h]   + ro_g[b*512 + 2*h];
  float v1 = RO[(long)m*512 + 2*h+1] + ro_g[b*512 + 2*h+1];
  outp[O_GOUT + o] = fmaxf(v0,v1);
}

extern "C" void kernel_launch(void* const* d_in, const int* in_sizes, int n_in,
                              void* d_out, int out_size, void* d_ws, size_t ws_size,
                              hipStream_t stream)
{
  (void)in_sizes; (void)n_in; (void)out_size; (void)ws_size;
  const int*   y       = (const int*)d_in[0];
  const float* hidden  = (const float*)d_in[1];
  const float* context = (const float*)d_in[2];
  const float* padm    = (const float*)d_in[3];
  const float* init_att= (const float*)d_in[4];
  const float* coverage= (const float*)d_in[5];
  const float* gctx    = (const float*)d_in[6];
  const float* embW    = (const float*)d_in[7];
  const float* W_ih    = (const float*)d_in[8];
  const float* W_hh    = (const float*)d_in[9];
  const float* b_ih    = (const float*)d_in[10];
  const float* b_hh    = (const float*)d_in[11];
  const float* W_pre   = (const float*)d_in[12];
  const float* b_pre   = (const float*)d_in[13];
  const float* W_q     = (const float*)d_in[14];
  const float* W_v     = (const float*)d_in[15];
  const float* W_cov   = (const float*)d_in[16];
  const float* W_pg    = (const float*)d_in[17];
  const float* b_pg    = (const float*)d_in[18];
  const float* W_ro    = (const float*)d_in[19];
  const float* b_ro    = (const float*)d_in[20];
  float* out = (float*)d_out;

  char* wsb = (char*)d_ws;
  size_t off = 0;
  auto alloc = [&](size_t bytes)->char*{ char* p = wsb+off; off += (bytes+255)&~255UL; return p; };
  unsigned short* pre    = (unsigned short*)alloc(25600UL*512*2);
  unsigned short* ctxbf  = (unsigned short*)alloc(13107200UL*2);
  unsigned short* embU   = (unsigned short*)alloc(3200UL*512*2);
  unsigned short* wihbf  = (unsigned short*)alloc(1536UL*512*2);
  unsigned short* wpreT  = (unsigned short*)alloc(512UL*512*2);
  unsigned short* wroT   = (unsigned short*)alloc(512UL*2048*2);
  unsigned short* Wgru   = (unsigned short*)alloc(192UL*8192*2);
  unsigned short* WqP    = (unsigned short*)alloc(16UL*16384*2);
  float* gi_emb = (float*)alloc(3200UL*1536*4);
  float* RO     = (float*)alloc(3200UL*512*4);
  float* q_g    = (float*)alloc(64UL*512*4);
  float* ro_g   = (float*)alloc(64UL*512*4);
  float* gctxT  = (float*)alloc(512UL*64*4);
  unsigned short* h0bf = (unsigned short*)alloc(3200UL*512*2);
  unsigned short* h0bf_init = (unsigned short*)alloc(64UL*512*2);
  unsigned short* ctx0bf    = (unsigned short*)alloc(64UL*512*2);
  unsigned short* ctxA = (unsigned short*)alloc(3200UL*512*2);
  float* qpart  = (float*)alloc(16UL*64*512*4);
  float* energy = (float*)alloc(64UL*400*4);
  float* cov    = (float*)alloc(64UL*400*4);

  // converts + init
  conv_ctx <<<dim3(51200),dim3(256),0,stream>>>(context, ctxbf);
  conv_emb <<<dim3(6400), dim3(256),0,stream>>>(y, embW, embU);
  conv_wihd<<<dim3(3072), dim3(256),0,stream>>>(W_ih, wihbf);
  conv_preT<<<dim3(1024), dim3(256),0,stream>>>(W_pre, wpreT);
  conv_roT <<<dim3(4096), dim3(256),0,stream>>>(W_ro, wroT);
  conv_wgru<<<dim3(6144), dim3(256),0,stream>>>(W_ih, W_hh, Wgru);
  conv_wq2 <<<dim3(1024), dim3(256),0,stream>>>(W_q, WqP);
  k_init   <<<dim3(485),  dim3(256),0,stream>>>(hidden, init_att, gctx, coverage,
                                                h0bf_init, ctx0bf, gctxT, cov);

  // precompute GEMMs
  mfma_gemm<1,0><<<dim3(200,4),dim3(256),0,stream>>>(ctxbf,512, wpreT,512,0,  pre,   512, b_pre, 512);
  mfma_gemm<0,0><<<dim3(25,12),dim3(256),0,stream>>>(embU, 512, wihbf,512,0,  gi_emb,1536,b_ih, 512);
  mfma_gemm<0,0><<<dim3(25,4), dim3(256),0,stream>>>(embU, 512, wroT,2048,0,  RO,    512, b_ro, 512);
  small_gemm_kn<<<dim3(128),dim3(256),0,stream>>>(gctxT, W_q, 512, 512, nullptr, q_g, 512);
  small_gemm_kn<<<dim3(128),dim3(256),0,stream>>>(gctxT, W_ro,1536, 512, nullptr, ro_g, 512);

  // persistent cooperative scan
  {
    const unsigned short* pre_c = pre;  const unsigned short* ctxbf_c = ctxbf;
    unsigned short* ctxA_p = ctxA;      unsigned short* h0bf_p = h0bf;
    const unsigned short* ctx0_c = ctx0bf; const unsigned short* h0i_c = h0bf_init;
    const float* gi_c = gi_emb; const float* qg_c = q_g;
    const unsigned short* wgru_c = Wgru; const unsigned short* wqp_c = WqP;
    void* args[] = {
      (void*)&wgru_c, (void*)&wqp_c, (void*)&pre_c, (void*)&ctxbf_c,
      (void*)&ctxA_p, (void*)&h0bf_p, (void*)&ctx0_c, (void*)&h0i_c,
      (void*)&hidden, (void*)&gi_c, (void*)&b_hh, (void*)&qg_c,
      (void*)&qpart, (void*)&W_v, (void*)&W_cov, (void*)&padm,
      (void*)&cov, (void*)&energy, (void*)&out
    };
    hipLaunchCooperativeKernel(reinterpret_cast<void*>(k_scan),
                               dim3(256), dim3(256), args, 0, stream);
  }

  // post-pass
  mfma_gemm<0,1><<<dim3(25,4),dim3(256),0,stream>>>(h0bf,512, wroT,2048,512,  RO,512, nullptr, 512);
  mfma_gemm<0,1><<<dim3(25,4),dim3(256),0,stream>>>(ctxA,512, wroT,2048,1024, RO,512, nullptr, 512);
  k_pgen  <<<dim3(800), dim3(256),0,stream>>>(embU, h0bf, ctxA, W_pg, b_pg, out);
  k_maxout<<<dim3(3200),dim3(256),0,stream>>>(RO, ro_g, out);
}